// Round 11
// baseline (704.273 us; speedup 1.0000x reference)
//
#include <hip/hip_runtime.h>
#include <hip/hip_bf16.h>

// QuantizedLinear: out[8192,11008] = x[8192,4096] @ dequant(W)^T
// Round 11: R8 baseline (best steady-state) + hidden waits:
//  - VMCNT4 hoisted into the middle of each MFMA burst (was exposed at close)
//  - PhB closes with LGKM4 (only a-rolls have 1-barrier WAR; b1-next drains
//    at a free mid-PhA LGKM0 next phase)
//  - dequant + cvt fused into one launch
// Reverted R10's chunking / NT stores / LGKM0-at-open (steady-state regression).

#define IN_F   4096
#define OUT_F  11008
#define M_DIM  8192
#define NGROUP 32

typedef __bf16 bf16x8 __attribute__((ext_vector_type(8)));
typedef float  f32x4  __attribute__((ext_vector_type(4)));
typedef unsigned short u16;
typedef u16 u16x8v __attribute__((ext_vector_type(8)));

__device__ __forceinline__ u16 f2bf(float f) {
  union { float f; unsigned u; } v; v.f = f;
  unsigned u = v.u;
  return (u16)((u + 0x7fffu + ((u >> 16) & 1u)) >> 16);  // RNE
}

__device__ __forceinline__ void gload_lds16(const void* gsrc, void* ldst) {
  __builtin_amdgcn_global_load_lds(
      (const __attribute__((address_space(1))) void*)gsrc,
      (__attribute__((address_space(3))) void*)ldst, 16, 0, 0);
}

// ------------- fused prep: dequant W -> bf16, cvt x -> bf16 ----------------
__global__ __launch_bounds__(256) void prep(const int* __restrict__ qw,
                                            const int* __restrict__ qz,
                                            const float* __restrict__ sc,
                                            const float* __restrict__ x,
                                            u16* __restrict__ W,
                                            u16* __restrict__ Xb) {
  const int DQ = (IN_F / 2) * OUT_F / 4;  // 5,636,096 int4 chunks
  const int CV = M_DIM * IN_F / 8;        // 4,194,304 float4-pairs
  int stride = gridDim.x * blockDim.x;
  for (int idx = blockIdx.x * blockDim.x + threadIdx.x; idx < DQ + CV; idx += stride) {
    if (idx < DQ) {
      int j = idx << 2;
      int o = j >> 11;
      int g = (j >> 6) & 31;
      float z = (float)qz[(o << 5) + g];
      float s = sc[(o << 5) + g];
      int4 q = ((const int4*)qw)[idx];
      int qs0 = q.x, qs1 = q.y, qs2 = q.z, qs3 = q.w;
      u16x8v w;
      w[0] = f2bf(((float)(qs0 & 15) - z) * s);
      w[1] = f2bf(((float)((qs0 >> 4) & 15) - z) * s);
      w[2] = f2bf(((float)(qs1 & 15) - z) * s);
      w[3] = f2bf(((float)((qs1 >> 4) & 15) - z) * s);
      w[4] = f2bf(((float)(qs2 & 15) - z) * s);
      w[5] = f2bf(((float)((qs2 >> 4) & 15) - z) * s);
      w[6] = f2bf(((float)(qs3 & 15) - z) * s);
      w[7] = f2bf(((float)((qs3 >> 4) & 15) - z) * s);
      ((u16x8v*)W)[idx] = w;
    } else {
      int i = idx - DQ;
      float4 a = ((const float4*)x)[i * 2];
      float4 b = ((const float4*)x)[i * 2 + 1];
      u16x8v v;
      v[0] = f2bf(a.x); v[1] = f2bf(a.y); v[2] = f2bf(a.z); v[3] = f2bf(a.w);
      v[4] = f2bf(b.x); v[5] = f2bf(b.y); v[6] = f2bf(b.z); v[7] = f2bf(b.w);
      ((u16x8v*)Xb)[i] = v;
    }
  }
}

// ---------------- 256x256 bf16 GEMM, 2 phases/K-tile: C = A * B^T ----------
// 8 waves 2Mx4N, wave tile 128x64. A-half mh = rows [mh*128 + wr*64);
// B-half nh = cols [nh*128 + wc*32).
// VM ledger (steady): each phase tops +4 stages, mid-burst VMCNT4 drains the
// previous phase's 4 (issued ~1 phase ago, hidden under ks1 MFMAs).
// LGKM: PhA closes LGKM0 (a-rolls read A1(u) buf c, overwritten 1 barrier
// later). PhB closes LGKM4 (drains a-rolls; b1-next stays in flight, drained
// by PhA's mid LGKM0 ~600cyc later, before any overwrite - 2-barrier region).

#define BAR       __builtin_amdgcn_s_barrier()
#define SCHED0    __builtin_amdgcn_sched_barrier(0)
#define LGKM0     asm volatile("s_waitcnt lgkmcnt(0)" ::: "memory")
#define LGKM4     asm volatile("s_waitcnt lgkmcnt(4)" ::: "memory")
#define VMCNT0    asm volatile("s_waitcnt vmcnt(0)" ::: "memory")
#define VMCNT4    asm volatile("s_waitcnt vmcnt(4)" ::: "memory")
#define PRIO(p)   __builtin_amdgcn_s_setprio(p)

__global__ __launch_bounds__(512, 2) void gemm256(const u16* __restrict__ A,
                                                  const u16* __restrict__ B,
                                                  float* __restrict__ C) {
  constexpr int K = IN_F, N = OUT_F;
  constexpr int NT = K / 64;  // 64 K-tiles
  __shared__ __align__(16) u16 sA[2][256 * 64];
  __shared__ __align__(16) u16 sB[2][256 * 64];

  const int NTN = OUT_F / 256;           // 43
  const int NWG = (M_DIM / 256) * NTN;   // 1376 (divisible by 8)
  int bid = blockIdx.x;
  int wg  = (bid & 7) * (NWG / 8) + (bid >> 3);  // bijective XCD swizzle
  int tm = wg / NTN, tn = wg - tm * NTN;
  int m0 = tm * 256, n0 = tn * 256;

  int tid  = threadIdx.x;
  int lane = tid & 63;
  int wave = tid >> 6;
  int wr = wave >> 2, wc = wave & 3;

  // staging: thread covers row (tid>>3), phys 16B slot tid&7.
  // phys slot s at row r holds global col-slot s^(r&7)  (involution).
  int rstage = tid >> 3;                               // 0..63
  int gslot  = ((tid & 7) ^ (rstage & 7)) << 3;        // global col elem
  int ldsoff = rstage * 64 + ((tid & 7) << 3);         // linear LDS elem
  const u16* Ag = A + (size_t)(m0 + rstage) * K + gslot;
  const u16* Bg = B + (size_t)(n0 + rstage) * K + gslot;

#define STAGE_A(cb, h, kt) do {                                   \
    const u16* _g = Ag + (size_t)(h) * 128 * K + (kt) * 64;       \
    u16* _l = sA[cb] + (h) * 128 * 64 + ldsoff;                   \
    gload_lds16(_g, _l);                                          \
    gload_lds16(_g + (size_t)64 * K, _l + 64 * 64);               \
  } while (0)

#define STAGE_B(cb, h, kt) do {                                   \
    const u16* _g = Bg + (size_t)(h) * 128 * K + (kt) * 64;       \
    u16* _l = sB[cb] + (h) * 128 * 64 + ldsoff;                   \
    gload_lds16(_g, _l);                                          \
    gload_lds16(_g + (size_t)64 * K, _l + 64 * 64);               \
  } while (0)

  // fragment reads: lane reads row base+(lane&15), k-quad q=lane>>4, slice ks.
  // phys 16B slot = (ks*4+q) ^ (lane&7)   (row&7 == lane&7: all row bases %8==0)
  int q8  = lane >> 4;
  int sl0 = ((q8 ^ (lane & 7)) << 3);            // ks=0, elems
  int sl1 = (((q8 | 4) ^ (lane & 7)) << 3);      // ks=1
  int abase = (wr * 64 + (lane & 15)) * 64;      // within A-half
  int bbase = (wc * 32 + (lane & 15)) * 64;      // within B-half

  bf16x8 a_[8], b0_[4], b1_[4];
  f32x4 acc[8][4] = {};

#define LDA(cb, mh) do {                                          \
    const u16* _p = sA[cb] + abase + (mh) * 8192;                 \
    a_[0] = *(const bf16x8*)(_p + sl0);                           \
    a_[1] = *(const bf16x8*)(_p + sl1);                           \
    a_[2] = *(const bf16x8*)(_p + 1024 + sl0);                    \
    a_[3] = *(const bf16x8*)(_p + 1024 + sl1);                    \
    a_[4] = *(const bf16x8*)(_p + 2048 + sl0);                    \
    a_[5] = *(const bf16x8*)(_p + 2048 + sl1);                    \
    a_[6] = *(const bf16x8*)(_p + 3072 + sl0);                    \
    a_[7] = *(const bf16x8*)(_p + 3072 + sl1);                    \
  } while (0)

#define LDB(cb, nh, dst) do {                                     \
    const u16* _p = sB[cb] + bbase + (nh) * 8192;                 \
    dst[0] = *(const bf16x8*)(_p + sl0);                          \
    dst[1] = *(const bf16x8*)(_p + sl1);                          \
    dst[2] = *(const bf16x8*)(_p + 1024 + sl0);                   \
    dst[3] = *(const bf16x8*)(_p + 1024 + sl1);                   \
  } while (0)

  // ks-OUTER MFMA ordering (dep distance 8).
#define QUAD(mh, nh, bq) do {                                                  \
    _Pragma("unroll") for (int mf = 0; mf < 4; mf++)                           \
      _Pragma("unroll") for (int nf = 0; nf < 2; nf++)                         \
        acc[(mh)*4+mf][(nh)*2+nf] = __builtin_amdgcn_mfma_f32_16x16x32_bf16(   \
            a_[mf*2+0], bq[nf*2+0], acc[(mh)*4+mf][(nh)*2+nf], 0, 0, 0);       \
    _Pragma("unroll") for (int mf = 0; mf < 4; mf++)                           \
      _Pragma("unroll") for (int nf = 0; nf < 2; nf++)                         \
        acc[(mh)*4+mf][(nh)*2+nf] = __builtin_amdgcn_mfma_f32_16x16x32_bf16(   \
            a_[mf*2+1], bq[nf*2+1], acc[(mh)*4+mf][(nh)*2+nf], 0, 0, 0);       \
  } while (0)

  // rolling A-prefetch in the ks=1 pass; VMCNT4 hoisted between the passes
  // (hides the vm-wait under 8 MFMAs instead of exposing it at phase close).
#define QUAD_ROLLA_V(mh, nh, bq, rp) do {                                      \
    _Pragma("unroll") for (int mf = 0; mf < 4; mf++)                           \
      _Pragma("unroll") for (int nf = 0; nf < 2; nf++)                         \
        acc[(mh)*4+mf][(nh)*2+nf] = __builtin_amdgcn_mfma_f32_16x16x32_bf16(   \
            a_[mf*2+0], bq[nf*2+0], acc[(mh)*4+mf][(nh)*2+nf], 0, 0, 0);       \
    VMCNT4;                                                                    \
    _Pragma("unroll") for (int mf = 0; mf < 4; mf++) {                         \
      _Pragma("unroll") for (int nf = 0; nf < 2; nf++)                         \
        acc[(mh)*4+mf][(nh)*2+nf] = __builtin_amdgcn_mfma_f32_16x16x32_bf16(   \
            a_[mf*2+1], bq[nf*2+1], acc[(mh)*4+mf][(nh)*2+nf], 0, 0, 0);       \
      a_[mf*2+0] = *(const bf16x8*)((rp) + mf * 1024 + sl0);                   \
      a_[mf*2+1] = *(const bf16x8*)((rp) + mf * 1024 + sl1);                   \
    }                                                                          \
  } while (0)

  // Two phases per K-tile (buf c = u&1).
#define TILE2(c, u) do {                                          \
    int _k1 = ((u) + 1) & (NT - 1), _k2 = ((u) + 2) & (NT - 1);   \
    /* PhA: (0,0),(0,1) with a_=A0(u); stage A1(u+1)->c^1 and     \
       A0(u+2)->c; mid LGKM0 drains PhB(u-1)'s lazy b1-next;      \
       roll a_<-A1(u); close LGKM0 (a-roll WAR is 1 barrier). */  \
    STAGE_A((c) ^ 1, 1, _k1);                                     \
    STAGE_A(c, 0, _k2);                                           \
    PRIO(1);                                                      \
    QUAD(0, 0, b0_);                                              \
    LGKM0;                                                        \
    QUAD_ROLLA_V(0, 1, b1_, sA[c] + abase + 8192);                \
    PRIO(0); LGKM0; BAR;                                          \
    /* PhB: (1,0),(1,1) with a_=A1(u); stage B0,B1(u+2)->c;       \
       reload b0_,b1_<-B(u+1); roll a_<-A0(u+1); close LGKM4      \
       (drains a-rolls+b0-next; b1-next lazy, 2-barrier region).*/\
    STAGE_B(c, 0, _k2);                                           \
    STAGE_B(c, 1, _k2);                                           \
    PRIO(1);                                                      \
    QUAD(1, 0, b0_);                                              \
    LDB((c) ^ 1, 0, b0_);                                         \
    QUAD_ROLLA_V(1, 1, b1_, sA[(c) ^ 1] + abase);                 \
    LDB((c) ^ 1, 1, b1_);                                         \
    PRIO(0); LGKM4; BAR;                                          \
  } while (0)

  // prologue: stage tile0 (A0,A1,B0,B1) + A0(1); drain ALL, barrier, preload
  // frags; then stage B(1) so exactly {B(1) x4} precede PhA(0)'s top stages
  // in the VM FIFO (matches steady-state ledger: mid-VMCNT4 drains B(1)).
  STAGE_A(0, 0, 0); STAGE_A(0, 1, 0);
  STAGE_B(0, 0, 0); STAGE_B(0, 1, 0);
  STAGE_A(1, 0, 1);
  VMCNT0; BAR;
  SCHED0;
  asm volatile("" ::: "memory");
  LDA(0, 0);
  LDB(0, 0, b0_);
  LDB(0, 1, b1_);
  STAGE_B(1, 0, 1); STAGE_B(1, 1, 1);

#pragma unroll 1
  for (int u = 0; u < NT; u += 2) {
    TILE2(0, u);
    TILE2(1, u + 1);
  }

  // C/D layout: col = lane&15, row = (lane>>4)*4 + j
  // output row = (m>>2)*128 + wr*64 + (m&3)*16 + (lane>>4)*4 + j
  // output col = (n>>1)*128 + wc*32 + (n&1)*16 + (lane&15)
  float* Cp = C + (size_t)(m0 + wr * 64 + ((lane >> 4) << 2)) * N
                + n0 + wc * 32 + (lane & 15);
#pragma unroll
  for (int m = 0; m < 8; m++) {
    int roff = (m >> 2) * 128 + (m & 3) * 16;
#pragma unroll
    for (int n = 0; n < 4; n++) {
      int coff = (n >> 1) * 128 + (n & 1) * 16;
#pragma unroll
      for (int j = 0; j < 4; j++)
        Cp[(size_t)(roff + j) * N + coff] = acc[m][n][j];
    }
  }
}

// ---------------- exact fp32 fallback (only if ws too small) ---------------
__global__ __launch_bounds__(256) void naive_gemm(const float* __restrict__ x,
                                                  const int* __restrict__ qw,
                                                  const int* __restrict__ qz,
                                                  const float* __restrict__ sc,
                                                  float* __restrict__ out) {
  __shared__ float xs[IN_F];
  int m = blockIdx.y;
  int n = blockIdx.x * 256 + threadIdx.x;
  for (int i = threadIdx.x; i < IN_F; i += 256) xs[i] = x[(size_t)m * IN_F + i];
  __syncthreads();
  float acc = 0.f;
  const int* qrow = qw + (size_t)n * (IN_F / 2);
  for (int g = 0; g < NGROUP; g++) {
    float z = (float)qz[n * NGROUP + g];
    float s = sc[n * NGROUP + g];
    for (int t = 0; t < 64; t++) {
      int q = qrow[g * 64 + t];
      acc += xs[g * 128 + 2 * t] * ((float)(q & 15) - z) * s;
      acc += xs[g * 128 + 2 * t + 1] * ((float)((q >> 4) & 15) - z) * s;
    }
  }
  out[(size_t)m * OUT_F + n] = acc;
}

extern "C" void kernel_launch(void* const* d_in, const int* in_sizes, int n_in,
                              void* d_out, int out_size, void* d_ws, size_t ws_size,
                              hipStream_t stream) {
  const float* x  = (const float*)d_in[0];
  const int*   qw = (const int*)d_in[1];
  const int*   qz = (const int*)d_in[2];
  const float* sc = (const float*)d_in[3];
  float* out = (float*)d_out;

  const size_t WBYTES = (size_t)OUT_F * IN_F * 2;
  const size_t XBYTES = (size_t)M_DIM * IN_F * 2;

  if (ws_size >= WBYTES + XBYTES) {
    u16* Wb = (u16*)d_ws;
    u16* Xb = (u16*)((char*)d_ws + WBYTES);
    prep<<<4096, 256, 0, stream>>>(qw, qz, sc, x, Wb, Xb);
    gemm256<<<(M_DIM / 256) * (OUT_F / 256), 512, 0, stream>>>(Xb, Wb, out);
  } else {
    naive_gemm<<<dim3(OUT_F / 256, M_DIM), 256, 0, stream>>>(x, qw, qz, sc, out);
  }
}